// Round 5
// baseline (288.587 us; speedup 1.0000x reference)
//
#include <hip/hip_runtime.h>
#include <hip/hip_bf16.h>
#include <math.h>

// B=32, L1=L2=512, H=768.  All-fp16 MFMA pipeline, 6 launches:
//   cvt_all: xh,yh,Wh = fp16(x,y,W)           (one kernel, block-range split)
//   proj   : P[32768,768] = fp16(relu([xh;yh]@Wh^T+b))  (32x32x16 f16 MFMA)
//   scores : S = Px@Py^T per batch, mask -inf (16x16x32 f16 MFMA)
//   yT     : fp16 transpose of y per batch
//   softmax: alpha = fp16(softmax(S))
//   attn   : out = alpha @ y  via yT           (16x16x32 f16 MFMA)
// All GEMM staging via global_load_lds width=16, unpadded 64B LDS rows.

typedef _Float16 f16x8 __attribute__((ext_vector_type(8)));
typedef float f32x4 __attribute__((ext_vector_type(4)));
typedef float f32x16 __attribute__((ext_vector_type(16)));

__device__ __forceinline__ void gld_lds16(const void* g, void* l) {
  __builtin_amdgcn_global_load_lds(
      (const __attribute__((address_space(1))) unsigned*)g,
      (__attribute__((address_space(3))) unsigned*)l, 16, 0, 0);
}

// ------------- fp32 -> fp16 convert, x|y|W in one launch -------------------
__global__ __launch_bounds__(256) void cvt_all_kernel(
    const float* __restrict__ x, const float* __restrict__ y,
    const float* __restrict__ W, _Float16* __restrict__ xh,
    _Float16* __restrict__ yh, _Float16* __restrict__ Wh) {
  int blk = blockIdx.x;
  const float* src;
  _Float16* dst;
  if (blk < 6144) { src = x; dst = xh; }
  else if (blk < 12288) { src = y; dst = yh; blk -= 6144; }
  else { src = W; dst = Wh; blk -= 12288; }
  size_t i = ((size_t)blk * 256 + threadIdx.x) * 8;
  float4 a = *(const float4*)&src[i];
  float4 b = *(const float4*)&src[i + 4];
  _Float16 h[8] = {(_Float16)a.x, (_Float16)a.y, (_Float16)a.z, (_Float16)a.w,
                   (_Float16)b.x, (_Float16)b.y, (_Float16)b.z, (_Float16)b.w};
  *(uint4*)&dst[i] = *(uint4*)h;
}

// ---- proj: P[32768,768] = fp16(relu(A @ W^T + b)), K=768, 32x32x16 MFMA ---
__global__ __launch_bounds__(256) void proj_mfma_kernel(
    const _Float16* __restrict__ A, const _Float16* __restrict__ W,
    const float* __restrict__ bias, _Float16* __restrict__ P) {
  const int K = 768, N = 768;
  __shared__ _Float16 As[128 * 32], Bs[128 * 32];
  int bm = blockIdx.x * 128, bn = blockIdx.y * 128;
  int tid = threadIdx.x, lane = tid & 63, wave = tid >> 6;
  int wm = (wave & 1) * 64, wn = (wave >> 1) * 64;
  int r32 = lane & 31, g = lane >> 5;      // frag row / k-group
  int lrow = lane >> 2, lcol = (lane & 3) << 3;  // glds lane mapping

  f32x16 acc[2][2];
#pragma unroll
  for (int i = 0; i < 2; ++i)
#pragma unroll
    for (int j = 0; j < 2; ++j)
#pragma unroll
      for (int e = 0; e < 16; ++e) acc[i][j][e] = 0.f;

  for (int k0 = 0; k0 < K; k0 += 32) {
    __syncthreads();
#pragma unroll
    for (int t = 0; t < 2; ++t) {
      int row = wave * 32 + t * 16;
      gld_lds16(&A[(size_t)(bm + row + lrow) * K + k0 + lcol], &As[row * 32]);
      gld_lds16(&W[(size_t)(bn + row + lrow) * K + k0 + lcol], &Bs[row * 32]);
    }
    __syncthreads();
    f16x8 a[2][2], bb[2][2];
#pragma unroll
    for (int i = 0; i < 2; ++i)
#pragma unroll
      for (int h = 0; h < 2; ++h) {
        a[i][h] = *(const f16x8*)&As[(wm + 32 * i + r32) * 32 + h * 16 + g * 8];
        bb[i][h] = *(const f16x8*)&Bs[(wn + 32 * i + r32) * 32 + h * 16 + g * 8];
      }
#pragma unroll
    for (int i = 0; i < 2; ++i)
#pragma unroll
      for (int j = 0; j < 2; ++j)
#pragma unroll
        for (int h = 0; h < 2; ++h)
          acc[i][j] = __builtin_amdgcn_mfma_f32_32x32x16_f16(a[i][h], bb[j][h], acc[i][j], 0, 0, 0);
  }
  // C/D: col = lane&31, row = (e&3) + 8*(e>>2) + 4*(lane>>5)
#pragma unroll
  for (int i = 0; i < 2; ++i)
#pragma unroll
    for (int j = 0; j < 2; ++j) {
      int n = bn + wn + 32 * j + r32;
      float bv = bias[n];
#pragma unroll
      for (int e = 0; e < 16; ++e) {
        int row = (e & 3) + 8 * (e >> 2) + 4 * g;
        int m = bm + wm + 32 * i + row;
        P[(size_t)m * N + n] = (_Float16)fmaxf(acc[i][j][e] + bv, 0.f);
      }
    }
}

// ---- scores: S[b,512,512] = Px@Py^T fp32, mask -inf, K=768 ---------------
__global__ __launch_bounds__(256) void scores_mfma_kernel(
    const _Float16* __restrict__ Px, const _Float16* __restrict__ Py,
    const int* __restrict__ mask, float* __restrict__ S) {
  const int K = 768, L = 512;
  __shared__ _Float16 As[128 * 32], Bs[128 * 32];
  int b = blockIdx.z;
  size_t pb = (size_t)b * L * K;
  const int* mk = mask + (size_t)b * L;
  float* Sb = S + (size_t)b * L * L;
  int bm = blockIdx.x * 128, bn = blockIdx.y * 128;
  int tid = threadIdx.x, lane = tid & 63, wave = tid >> 6;
  int wm = (wave & 1) * 64, wn = (wave >> 1) * 64;
  int fr = lane & 15, fk = (lane >> 4) * 8;
  int lrow = lane >> 2, lcol = (lane & 3) << 3;

  f32x4 acc[4][4];
#pragma unroll
  for (int i = 0; i < 4; ++i)
#pragma unroll
    for (int j = 0; j < 4; ++j)
#pragma unroll
      for (int e = 0; e < 4; ++e) acc[i][j][e] = 0.f;

  for (int k0 = 0; k0 < K; k0 += 32) {
    __syncthreads();
#pragma unroll
    for (int t = 0; t < 2; ++t) {
      int row = wave * 32 + t * 16;
      gld_lds16(&Px[pb + (size_t)(bm + row + lrow) * K + k0 + lcol], &As[row * 32]);
      gld_lds16(&Py[pb + (size_t)(bn + row + lrow) * K + k0 + lcol], &Bs[row * 32]);
    }
    __syncthreads();
    f16x8 a[4], bb[4];
#pragma unroll
    for (int i = 0; i < 4; ++i) {
      a[i] = *(const f16x8*)&As[(wm + i * 16 + fr) * 32 + fk];
      bb[i] = *(const f16x8*)&Bs[(wn + i * 16 + fr) * 32 + fk];
    }
#pragma unroll
    for (int i = 0; i < 4; ++i)
#pragma unroll
      for (int j = 0; j < 4; ++j)
        acc[i][j] = __builtin_amdgcn_mfma_f32_16x16x32_f16(a[i], bb[j], acc[i][j], 0, 0, 0);
  }
#pragma unroll
  for (int i = 0; i < 4; ++i)
#pragma unroll
    for (int r = 0; r < 4; ++r) {
      int m = bm + wm + i * 16 + (lane >> 4) * 4 + r;
#pragma unroll
      for (int j = 0; j < 4; ++j) {
        int n = bn + wn + j * 16 + fr;
        Sb[(size_t)m * L + n] = mk[n] ? -INFINITY : acc[i][j][r];
      }
    }
}

// ---------------- softmax rows of 512, fp32 in -> fp16 alpha out ----------
__global__ __launch_bounds__(256) void softmax_kernel(
    const float* __restrict__ S, _Float16* __restrict__ Alpha) {
  size_t row = blockIdx.x;
  const float* p = S + row * 512;
  _Float16* q = Alpha + row * 512;
  int tid = threadIdx.x, lane = tid & 63, wid = tid >> 6;
  float2 v = *(const float2*)(p + tid * 2);

  float m = fmaxf(v.x, v.y);
#pragma unroll
  for (int off = 32; off > 0; off >>= 1) m = fmaxf(m, __shfl_down(m, off));
  __shared__ float redm[4], reds[4];
  if (lane == 0) redm[wid] = m;
  __syncthreads();
  m = fmaxf(fmaxf(redm[0], redm[1]), fmaxf(redm[2], redm[3]));

  float e0 = __expf(v.x - m);
  float e1 = __expf(v.y - m);
  float s = e0 + e1;
#pragma unroll
  for (int off = 32; off > 0; off >>= 1) s += __shfl_down(s, off);
  if (lane == 0) reds[wid] = s;
  __syncthreads();
  s = reds[0] + reds[1] + reds[2] + reds[3];
  float inv = 1.0f / s;
  q[tid * 2] = (_Float16)(e0 * inv);
  q[tid * 2 + 1] = (_Float16)(e1 * inv);
}

// -------- yT: y [b,512,768] fp32 -> yT [b,768,512] fp16 (RNE) -------------
__global__ __launch_bounds__(256) void yT_kernel(const float* __restrict__ Y,
                                                 _Float16* __restrict__ YT) {
  __shared__ _Float16 T[64][65];
  int b = blockIdx.z;
  int n0 = blockIdx.x * 64, h0 = blockIdx.y * 64;
  const float* Yb = Y + (size_t)b * 512 * 768;
  _Float16* Tb = YT + (size_t)b * 768 * 512;
  int tid = threadIdx.x;
  int r = tid >> 4, c = (tid & 15) << 2;
#pragma unroll
  for (int i = 0; i < 4; ++i) {
    int rr = r + i * 16;
    float4 v = *(const float4*)&Yb[(size_t)(n0 + rr) * 768 + h0 + c];
    T[c + 0][rr] = (_Float16)v.x;
    T[c + 1][rr] = (_Float16)v.y;
    T[c + 2][rr] = (_Float16)v.z;
    T[c + 3][rr] = (_Float16)v.w;
  }
  __syncthreads();
  int hr = tid >> 2, nc = (tid & 3) << 4;
  _Float16* dst = &Tb[(size_t)(h0 + hr) * 512 + n0 + nc];
  _Float16 tmp[16];
#pragma unroll
  for (int j = 0; j < 16; ++j) tmp[j] = T[hr][nc + j];
  *(uint4*)&dst[0] = *(uint4*)&tmp[0];
  *(uint4*)&dst[8] = *(uint4*)&tmp[8];
}

// ---- attn: O[b,512,768] = alpha @ y, K=512, fp16 MFMA --------------------
__global__ __launch_bounds__(256) void attn_mfma_kernel(
    const _Float16* __restrict__ Alpha, const _Float16* __restrict__ YT,
    float* __restrict__ O) {
  const int L = 512, H = 768;
  __shared__ _Float16 As[128 * 32], Bs[128 * 32];
  int b = blockIdx.z;
  const _Float16* Ab = Alpha + (size_t)b * L * L;
  const _Float16* Yb = YT + (size_t)b * H * L;
  float* Ob = O + (size_t)b * L * H;
  int bm = blockIdx.x * 128, bn = blockIdx.y * 128;
  int tid = threadIdx.x, lane = tid & 63, wave = tid >> 6;
  int wm = (wave & 1) * 64, wn = (wave >> 1) * 64;
  int fr = lane & 15, fk = (lane >> 4) * 8;
  int lrow = lane >> 2, lcol = (lane & 3) << 3;

  f32x4 acc[4][4];
#pragma unroll
  for (int i = 0; i < 4; ++i)
#pragma unroll
    for (int j = 0; j < 4; ++j)
#pragma unroll
      for (int e = 0; e < 4; ++e) acc[i][j][e] = 0.f;

  for (int k0 = 0; k0 < L; k0 += 32) {
    __syncthreads();
#pragma unroll
    for (int t = 0; t < 2; ++t) {
      int row = wave * 32 + t * 16;
      gld_lds16(&Ab[(size_t)(bm + row + lrow) * L + k0 + lcol], &As[row * 32]);
      gld_lds16(&Yb[(size_t)(bn + row + lrow) * L + k0 + lcol], &Bs[row * 32]);
    }
    __syncthreads();
    f16x8 a[4], bb[4];
#pragma unroll
    for (int i = 0; i < 4; ++i) {
      a[i] = *(const f16x8*)&As[(wm + i * 16 + fr) * 32 + fk];
      bb[i] = *(const f16x8*)&Bs[(wn + i * 16 + fr) * 32 + fk];
    }
#pragma unroll
    for (int i = 0; i < 4; ++i)
#pragma unroll
      for (int j = 0; j < 4; ++j)
        acc[i][j] = __builtin_amdgcn_mfma_f32_16x16x32_f16(a[i], bb[j], acc[i][j], 0, 0, 0);
  }
#pragma unroll
  for (int i = 0; i < 4; ++i)
#pragma unroll
    for (int r = 0; r < 4; ++r) {
      int m = bm + wm + i * 16 + (lane >> 4) * 4 + r;
#pragma unroll
      for (int j = 0; j < 4; ++j) {
        int h = bn + wn + j * 16 + fr;
        Ob[(size_t)m * H + h] = acc[i][j][r];
      }
    }
}

extern "C" void kernel_launch(void* const* d_in, const int* in_sizes, int n_in,
                              void* d_out, int out_size, void* d_ws, size_t ws_size,
                              hipStream_t stream) {
  const float* x = (const float*)d_in[0];   // [32,512,768]
  const float* y = (const float*)d_in[1];   // [32,512,768]
  const int* y_mask = (const int*)d_in[2];  // [32,512]
  const float* W = (const float*)d_in[3];   // [768,768]
  const float* b = (const float*)d_in[4];   // [768]
  float* out = (float*)d_out;               // [32,512,768]

  const size_t E = (size_t)16384 * 768;     // 12,582,912 elems / fp16 plane
  _Float16* xh = (_Float16*)d_ws;           // 25.2 MB  (yh contiguous after)
  _Float16* yh = xh + E;                    // 25.2 MB
  _Float16* Px = yh + E;                    // 25.2 MB  (Py contiguous after)
  _Float16* Py = Px + E;                    // 25.2 MB
  float* S = (float*)(Py + E);              // 33.6 MB
  _Float16* Wh = (_Float16*)(S + (size_t)32 * 512 * 512);  // 1.2 MB
  _Float16* yT = Wh + (size_t)768 * 768;    // 25.2 MB
  _Float16* alpha = yT + E;                 // 16.8 MB  (total ~177 MB < 256 MiB)

  dim3 blk(256);
  cvt_all_kernel<<<dim3(12576), blk, 0, stream>>>(x, y, W, xh, yh, Wh);
  // merged proj over M=32768 ([xh;yh] -> [Px;Py])
  proj_mfma_kernel<<<dim3(256, 6), blk, 0, stream>>>(xh, Wh, b, Px);
  scores_mfma_kernel<<<dim3(4, 4, 32), blk, 0, stream>>>(Px, Py, y_mask, S);
  yT_kernel<<<dim3(8, 12, 32), blk, 0, stream>>>(y, yT);
  softmax_kernel<<<dim3(32 * 512), blk, 0, stream>>>(S, alpha);
  attn_mfma_kernel<<<dim3(4, 6, 32), blk, 0, stream>>>(alpha, yT, out);
}